// Round 9
// baseline (1171.300 us; speedup 1.0000x reference)
//
#include <hip/hip_runtime.h>
#include <hip/hip_bf16.h>

// B=8, T=2048, E=1024, D=DK*H=1024 (heads fused in reference math)
//   QKV = x @ [Wq|Wk|Wv]  fused GEMM  [16384 x 3072] bf16 (V stored transposed);
//         m-blocks entirely beyond len[b] skip compute and store zeros.
//   energy[b] = Q_b K_b^T  fp16; n-blocks bn>=len skipped; m-blocks bm>=len
//         store exact zeros (Q rows are zero) without compute.
//   lengths[b] = #nonzero rows of x[b]
//   P = softmax(mask(energy)/8) bf16 in place over fp16 rows (one row per wave)
//   out[b] = P_b V_b  fp32; K-loop clamped to round64(len[b]).
//
// R17: R8 regressed (27% MfmaUtil): 3 domains x 16-MFMA visits lost to R7's
// 2 domains x 32-MFMA visits. Controlling variable = MFMA demand per SIMD =
// waves/SIMD x MFMA-cyc/visit (one 16x16x32 ~ 19.4 cyc/SIMD). This round
// maximizes it: SINGLE-buffered 128x128/BK=64 -> 32 KiB LDS -> FOUR blocks/CU
// (launch_bounds(256,4), VGPR ~88 <= 128). Per tile:
//   stage(8 gloads) -> vmcnt(0) -> bar -> 16 asm ds_reads -> lgkm(8) ->
//   16 MFMA -> lgkm(0) -> 16 MFMA -> bar
// Staging drain (~600cyc) is exposed per-block but covered by 3 other
// independent blocks (m114 implicit overlap). Demand/SIMD = 4x620 = 2480 cyc
// vs ~1600-cyc solo slot -> MFMA pipe oversubscribed -> pipe-bound.
// Epilogues/swizzle/grids = R7 verbatim (verified); only K-loop + LDS change.
// ws = 140,509,440 B: lengths 256B | x16 32MB | WT 6MB | VT 32MB | E 64MB fp16.

typedef unsigned short u16;
typedef __bf16 bf16x8 __attribute__((ext_vector_type(8)));
typedef float f32x4 __attribute__((ext_vector_type(4)));
typedef unsigned short us8 __attribute__((ext_vector_type(8)));

__device__ __forceinline__ u16 f2bf(float f) {
    union { float f; unsigned u; } x; x.f = f;
    unsigned r = x.u + 0x7FFFu + ((x.u >> 16) & 1u);   // RNE
    return (u16)(r >> 16);
}
__device__ __forceinline__ u16 f2h(float f) {
    union { _Float16 h; u16 u; } c; c.h = (_Float16)f;
    return c.u;
}
__device__ __forceinline__ float h2f(u16 b) {
    union { u16 u; _Float16 h; } c; c.u = b;
    return (float)c.h;
}

__device__ __forceinline__ void gload_lds16(const void* g, void* l) {
    __builtin_amdgcn_global_load_lds(
        (const __attribute__((address_space(1))) unsigned*)g,
        (__attribute__((address_space(3))) unsigned*)l, 16, 0, 0);
}

// 32-bit LDS byte offset of a __shared__ object (addrspace(3) ptrs are 32-bit)
__device__ __forceinline__ unsigned lds_off(const void* p) {
    return (unsigned)(size_t)(const __attribute__((address_space(3))) char*)p;
}
// opaque LDS read: no alias edge to global_load_lds -> no compiler vmcnt drain
__device__ __forceinline__ bf16x8 ds_read16(unsigned a) {
    bf16x8 r;
    asm volatile("ds_read_b128 %0, %1" : "=v"(r) : "v"(a));
    return r;
}

// ---------------------------------------------------------------- cast x -> bf16
__global__ void cast_x(const float* __restrict__ x, u16* __restrict__ o) {
    int i = blockIdx.x * 256 + threadIdx.x;          // float4 index
    float4 v = ((const float4*)x)[i];
    ushort4 u;
    u.x = f2bf(v.x); u.y = f2bf(v.y); u.z = f2bf(v.z); u.w = f2bf(v.w);
    ((ushort4*)o)[i] = u;
}

// ------------------------------------------------- W[e][n] -> WT[n][e] bf16, x3
__global__ void transpose_cast_w(const float* __restrict__ Wq,
                                 const float* __restrict__ Wk,
                                 const float* __restrict__ Wv,
                                 u16* __restrict__ WT) {
    __shared__ float tile[32][33];
    const float* W = (blockIdx.z == 0) ? Wq : (blockIdx.z == 1) ? Wk : Wv;
    u16* T = WT + (size_t)blockIdx.z * 1048576;
    int n0 = blockIdx.x * 32, e0 = blockIdx.y * 32;
    int tx = threadIdx.x, ty = threadIdx.y;
#pragma unroll
    for (int j = 0; j < 4; ++j) {
        int e = ty + j * 8;
        tile[e][tx] = W[(size_t)(e0 + e) * 1024 + (n0 + tx)];
    }
    __syncthreads();
#pragma unroll
    for (int j = 0; j < 4; ++j) {
        int n = ty + j * 8;
        T[(size_t)(n0 + n) * 1024 + (e0 + tx)] = f2bf(tile[tx][n]);
    }
}

// ----------------------------------------------------- lengths[b] from x rows
__global__ void calc_lengths(const float* __restrict__ x, int* __restrict__ len) {
    int b = blockIdx.x, tid = threadIdx.x;
    int cnt = 0;
    for (int t = tid; t < 2048; t += 256) {
        float4 v = *(const float4*)(x + ((size_t)b * 2048 + t) * 1024);
        cnt += (v.x != 0.f || v.y != 0.f || v.z != 0.f || v.w != 0.f) ? 1 : 0;
    }
#pragma unroll
    for (int off = 32; off; off >>= 1) cnt += __shfl_xor(cnt, off);
    __shared__ int red[4];
    int wid = tid >> 6, lane = tid & 63;
    if (!lane) red[wid] = cnt;
    __syncthreads();
    if (tid == 0) len[b] = red[0] + red[1] + red[2] + red[3];
}

// ------------------------------------------------------------- bf16 NT GEMM
// 128x128 tile, BK=64, single-buffered LDS, 4 blocks/CU.
// MODE 3: fused-QKV routing (y 0-7 Q, 8-15 K, 16-23 V transposed into Cv2)
// MODE 4: energy fp16; n-blocks bn>=len return; m-blocks bm>=len store zeros
// MODE 5: PV fp32; K clamped to round64(len)

#define SBAR0 __builtin_amdgcn_sched_barrier(0)

#define STAGE_T(KT) do { \
  _Pragma("unroll") for (int j_ = 0; j_ < 4; ++j_) \
      gload_lds16(A + offA[j_] + (size_t)(KT) * 64, &As[ldsC[j_]]); \
  _Pragma("unroll") for (int j_ = 0; j_ < 4; ++j_) \
      gload_lds16(B + offB[j_] + (size_t)(KT) * 64, &Bs[ldsC[j_]]); \
} while (0)

#define LD_A(S) do { \
  _Pragma("unroll") for (int mt_ = 0; mt_ < 4; ++mt_) \
    af[S][mt_] = ds_read16(rowA[mt_] + ((S) ? swz1 : swz0)); \
} while (0)
#define LD_B(S) do { \
  _Pragma("unroll") for (int nt_ = 0; nt_ < 4; ++nt_) \
    bf[S][nt_] = ds_read16(rowB[nt_] + ((S) ? swz1 : swz0)); \
} while (0)

#define MFMA_S(S) do { \
  _Pragma("unroll") for (int mt_ = 0; mt_ < 4; ++mt_) \
  _Pragma("unroll") for (int nt_ = 0; nt_ < 4; ++nt_) \
    acc[mt_][nt_] = __builtin_amdgcn_mfma_f32_16x16x32_bf16( \
        af[S][mt_], bf[S][nt_], acc[mt_][nt_], 0, 0, 0); \
} while (0)

template <int MODE>
__global__ __launch_bounds__(256, 4)   // 4 waves; 4 blocks/CU (32 KiB LDS each)
void gemm_bt(const u16* __restrict__ A, int lda, size_t sA,
             const u16* __restrict__ B, int ldb, size_t sB,
             void* __restrict__ Cv, void* __restrict__ Cv2,
             int ldc, size_t sC, int Kdim, const int* __restrict__ lenp) {
    __shared__ u16 As[128 * 64];    // 16 KiB, single buffer
    __shared__ u16 Bs[128 * 64];    // 16 KiB
    const int tid = threadIdx.x;
    const int bz  = blockIdx.z;
    A += (size_t)bz * sA;
    B += (size_t)bz * sB;
    const size_t bm = (size_t)blockIdx.x * 128, bn = (size_t)blockIdx.y * 128;

    bool skip = false;
    int kEnd = Kdim;
    if (MODE == 3) {
        int lenz = lenp[bm >> 11];
        skip = ((int)(bm & 2047) >= lenz);           // whole tile rows are zero
    } else if (MODE == 4) {
        int lenz = lenp[bz];
        if ((int)bn >= lenz) return;                 // cols fully masked: unread
        skip = ((int)bm >= lenz);                    // Q rows zero -> energy 0
    } else if (MODE == 5) {
        int lenz = lenp[bz];
        int r64 = (lenz + 63) & ~63;
        kEnd = r64 < Kdim ? r64 : Kdim;              // P cols >= len are zeros
    }

    const int wid = tid >> 6, lane = tid & 63;
    const int wm = wid >> 1, wn = wid & 1;           // 2M x 2N wave grid
    const int q = lane >> 4, r = lane & 15;

    // staging: each matrix tile = 1024 x 16B chunks; thread owns c = j*256+tid.
    // chunk c -> linear LDS byte c*16 (wave-contiguous); global source column
    // pre-swizzled so LDS[linear] == swizzled layout (rule #21).
    size_t offA[4], offB[4]; int ldsC[4];
#pragma unroll
    for (int j = 0; j < 4; ++j) {
        int c = j * 256 + tid;
        int row = c >> 3;
        int c16 = (c & 7) ^ (row & 7);               // involution swizzle
        offA[j] = (size_t)(bm + row) * lda + c16 * 8;
        offB[j] = (size_t)(bn + row) * ldb + c16 * 8;
        ldsC[j] = c * 8;
    }

    // precomputed LDS read addresses: row base + swizzled 16B chunk
    unsigned rowA[4], rowB[4], swz0, swz1;
    {
        unsigned asB = lds_off(&As[0]), bsB = lds_off(&Bs[0]);
        swz0 = (unsigned)((q ^ (r & 7)) * 16);
        swz1 = (unsigned)(((q + 4) ^ (r & 7)) * 16);
#pragma unroll
        for (int mt = 0; mt < 4; ++mt)
            rowA[mt] = asB + (unsigned)((wm * 64 + mt * 16 + r) * 128);
#pragma unroll
        for (int nt = 0; nt < 4; ++nt)
            rowB[nt] = bsB + (unsigned)((wn * 64 + nt * 16 + r) * 128);
    }

    f32x4 acc[4][4] = {};

    if (!skip) {
        const int NT = kEnd >> 6;                    // >= 16 always (len>=1024)
        for (int t = 0; t < NT; ++t) {
            bf16x8 af[2][4], bf[2][4];
            // stage tile t (8 x global_load_lds); drain; block-wide visibility
            STAGE_T(t);
            SBAR0;
            asm volatile("s_waitcnt vmcnt(0)" ::: "memory");
            __builtin_amdgcn_s_barrier();            // writes visible to all
            SBAR0;
            // 16 ds_reads: khalf0 (A,B) then khalf1 (A,B)
            LD_A(0); LD_B(0);
            LD_A(1); LD_B(1);
            asm volatile("s_waitcnt lgkmcnt(8)" ::: "memory");  // khalf0 ready
            SBAR0;
            __builtin_amdgcn_s_setprio(1);
            MFMA_S(0);                               // khalf1 lands underneath
            __builtin_amdgcn_s_setprio(0);
            SBAR0;
            asm volatile("s_waitcnt lgkmcnt(0)" ::: "memory");  // khalf1 ready
            SBAR0;
            __builtin_amdgcn_s_setprio(1);
            MFMA_S(1);
            __builtin_amdgcn_s_setprio(0);
            SBAR0;
            __builtin_amdgcn_s_barrier();            // reads done before next stage
            SBAR0;
        }
    }

    // C/D layout per 16x16 fragment: col = lane&15, row = (lane>>4)*4 + i
    // acc[mt][nt]: row = wm*64 + mt*16 + q*4 + i, col = wn*64 + nt*16 + r
    if (MODE == 5) {
        float* C = (float*)Cv + (size_t)bz * sC;
#pragma unroll
        for (int mt = 0; mt < 4; ++mt) {
            size_t row = bm + wm * 64 + mt * 16 + q * 4;
#pragma unroll
            for (int nt = 0; nt < 4; ++nt) {
                size_t col = bn + wn * 64 + nt * 16 + r;
#pragma unroll
                for (int i = 0; i < 4; ++i)
                    C[(row + i) * (size_t)ldc + col] = acc[mt][nt][i];
            }
        }
    } else if (MODE == 4) {
        u16* C = (u16*)Cv + (size_t)bz * sC;
#pragma unroll
        for (int mt = 0; mt < 4; ++mt) {
            size_t row = bm + wm * 64 + mt * 16 + q * 4;
#pragma unroll
            for (int nt = 0; nt < 4; ++nt) {
                size_t col = bn + wn * 64 + nt * 16 + r;
#pragma unroll
                for (int i = 0; i < 4; ++i)
                    C[(row + i) * (size_t)ldc + col] = f2h(acc[mt][nt][i]);
            }
        }
    } else {  // MODE 3: fused QKV epilogue, region uniform per block
        int region = blockIdx.y >> 3;                 // 0:Q 1:K 2:V (8 y each)
        if (region < 2) {
            u16* C = (u16*)Cv + (size_t)region * 16777216;  // Q or K [16384x1024]
            size_t cb = bn - (size_t)region * 1024;
#pragma unroll
            for (int mt = 0; mt < 4; ++mt) {
                size_t row = bm + wm * 64 + mt * 16 + q * 4;
#pragma unroll
                for (int nt = 0; nt < 4; ++nt) {
                    size_t col = cb + wn * 64 + nt * 16 + r;
#pragma unroll
                    for (int i = 0; i < 4; ++i)
                        C[(row + i) * 1024 + col] = f2bf(acc[mt][nt][i]);
                }
            }
        } else {
            // VT[b][d][t] = V[b*2048+t][d]; b = bm>>11 is BLOCK-UNIFORM
            // (128-row tiles never straddle the 2048-row batch boundary).
            // Each lane owns 4 consecutive t at fixed d -> one ushort4 store.
            u16* Cb = (u16*)Cv2 + (bm >> 11) * (size_t)(1024 * 2048)
                      + (bn - 2048) * 2048 + (bm & 2047);
#pragma unroll
            for (int nt = 0; nt < 4; ++nt) {
                int cI = wn * 64 + nt * 16 + r;
#pragma unroll
                for (int mt = 0; mt < 4; ++mt) {
                    int tI = wm * 64 + mt * 16 + q * 4;
                    ushort4 o;
                    o.x = f2bf(acc[mt][nt][0]);
                    o.y = f2bf(acc[mt][nt][1]);
                    o.z = f2bf(acc[mt][nt][2]);
                    o.w = f2bf(acc[mt][nt][3]);
                    *(ushort4*)(Cb + (size_t)cI * 2048 + tI) = o;
                }
            }
        }
    }
}

// ---- masked softmax, ONE ROW PER WAVE: fp16 row in, bf16 P in place (full row)
// Read and write both use us8 chunks: chunk c = j*64+lane covers cols c*8..c*8+7.
__global__ void softmax_rows_w(u16* __restrict__ E, const int* __restrict__ lengths) {
    int row  = blockIdx.x * 4 + (threadIdx.x >> 6);   // 16384 rows, 4 waves/block
    int lane = threadIdx.x & 63;
    int len  = lengths[row >> 11];
    u16* e = E + (size_t)row * 2048;

    float vals[32];
#pragma unroll
    for (int j = 0; j < 4; ++j) {
        us8 v = ((const us8*)e)[j * 64 + lane];
#pragma unroll
        for (int w = 0; w < 8; ++w) vals[j * 8 + w] = h2f(v[w]);
    }

    float m = -3.4e38f;
#pragma unroll
    for (int j = 0; j < 4; ++j) {
        int base = (j * 64 + lane) * 8;
#pragma unroll
        for (int w = 0; w < 8; ++w)
            if (base + w < len) m = fmaxf(m, vals[j * 8 + w]);
    }
#pragma unroll
    for (int off = 32; off; off >>= 1) m = fmaxf(m, __shfl_xor(m, off));

    const float C = 0.18033688011112042f;   // log2(e)/8  (scale 1/sqrt(64))
    float p[32]; float s = 0.f;
#pragma unroll
    for (int j = 0; j < 4; ++j) {
        int base = (j * 64 + lane) * 8;
#pragma unroll
        for (int w = 0; w < 8; ++w) {
            float v = (base + w < len) ? exp2f((vals[j * 8 + w] - m) * C) : 0.f;
            p[j * 8 + w] = v;
            s += v;
        }
    }
#pragma unroll
    for (int off = 32; off; off >>= 1) s += __shfl_xor(s, off);
    float rinv = 1.0f / s;

    // bf16 P over the fp16 row, identical chunk mapping as the read
#pragma unroll
    for (int j = 0; j < 4; ++j) {
        us8 o;
#pragma unroll
        for (int w = 0; w < 8; ++w) o[w] = f2bf(p[j * 8 + w] * rinv);
        ((us8*)e)[j * 64 + lane] = o;
    }
}

// ------------------------------------------------------------------ launch
extern "C" void kernel_launch(void* const* d_in, const int* in_sizes, int n_in,
                              void* d_out, int out_size, void* d_ws, size_t ws_size,
                              hipStream_t stream) {
    const float* x  = (const float*)d_in[0];
    const float* Wq = (const float*)d_in[1];
    const float* Wk = (const float*)d_in[2];
    const float* Wv = (const float*)d_in[3];
    float* out = (float*)d_out;
    char* ws = (char*)d_ws;

    const size_t SB  = 2097152;      // u16 elems per batch [2048x1024]
    const size_t SBe = 4194304;      // u16 elems per batch energy [2048x2048]

    // ws: lengths 256B | x16 32MB | WT 6MB | VT 32MB | E 64MB fp16 = 140,509,440 B
    if (ws_size < 140509440ULL) return;
    int* lengths = (int*)ws;
    u16* x16 = (u16*)(ws + 256);
    u16* WT  = (u16*)(ws + 33554688);
    u16* VT  = (u16*)(ws + 39846144);
    u16* E   = (u16*)(ws + 73400576);
    u16* Qb  = (u16*)d_out;                          // Q,K parked in d_out (64 MiB)
    u16* Kb  = Qb + 16777216;

    cast_x<<<dim3(16384), dim3(256), 0, stream>>>(x, x16);
    transpose_cast_w<<<dim3(32, 32, 3), dim3(32, 8), 0, stream>>>(Wq, Wk, Wv, WT);
    calc_lengths<<<dim3(8), dim3(256), 0, stream>>>(x, lengths);

    // fused QKV: x16[16384x1024] @ WT[3072x1024]^T -> Q,K (d_out) + VT (ws)
    gemm_bt<3><<<dim3(128, 24, 1), 256, 0, stream>>>(x16, 1024, 0, WT, 1024, 0,
                                                     Qb, VT, 1024, 0, 1024, lengths);

    // energy[b] = Q_b K_b^T -> fp16 E; bn>=len skipped, bm>=len zero-filled
    gemm_bt<4><<<dim3(16, 16, 8), 256, 0, stream>>>(Qb, 1024, SB, Kb, 1024, SB,
                                                    E, nullptr, 2048, SBe, 1024, lengths);

    // masked softmax -> bf16 P in place (one row per wave)
    softmax_rows_w<<<dim3(4096), dim3(256), 0, stream>>>(E, lengths);

    // out[b] = P_b V_b = P_b (VT_b)^T; K clamped to round64(len[b])
    gemm_bt<5><<<dim3(16, 8, 8), 256, 0, stream>>>(E, 2048, SBe, VT, 2048, SB,
                                                   out, nullptr, 1024, SB, 2048, lengths);
}

// Round 10
// 371.494 us; speedup vs baseline: 3.1529x; 3.1529x over previous
//
#include <hip/hip_runtime.h>
#include <hip/hip_bf16.h>

// B=8, T=2048, E=1024, D=DK*H=1024 (heads fused in reference math)
//   QKV = x @ [Wq|Wk|Wv]  fused GEMM  [16384 x 3072] bf16 (V stored transposed);
//         m-blocks entirely beyond len[b] skip compute and store zeros.
//   energy[b] = Q_b K_b^T  fp16; n-blocks bn>=len skipped; m-blocks bm>=len
//         store exact zeros (Q rows are zero) without compute.
//   lengths[b] = #nonzero rows of x[b]
//   P = softmax(mask(energy)/8) bf16 in place over fp16 rows (one row per wave)
//   out[b] = P_b V_b  fp32; K-loop clamped to round64(len[b]).
//
// R18: R9's 4-blk/CU single-buffer collapsed L2 reuse (FETCH 97->480 MB,
// MfmaUtil 7%): the counted-vmcnt wait length is set by WHERE staging loads
// hit (L2 ~200cyc vs far ~900cyc, m126). Revert to R7's verified structure
// (best: 111.7us QKV, 31% MfmaUtil) and change ONE thing: XCD-aware block
// placement for QKV (T1). HW round-robins consecutive blockIdx.x across the
// 8 XCDs; QKV is launched 1-D (3072) and decoded so XCD c owns x-strip rows
// [c*1024,(c+1)*1024) (then strip c+8), sweeping all 24 y-panels while its
// 2-MB A-strip stays hot in the XCD-private L2 (live set ~2MB A + ~2MB B =
// 4MB = L2). A-staging becomes L2-hit -> vmcnt windows shrink ~3x. Energy/PV
// grids unchanged (x%8 already keeps 2 panels/XCD hot; z-scatter balances
// len skew). Decode bijective: (c,half,xl,y) <-> (x,y). Schedule/layout/
// epilogues byte-identical to R7 (2 barriers/K-tile, 2 blocks/CU, dbuf).
// ws = 140,509,440 B: lengths 256B | x16 32MB | WT 6MB | VT 32MB | E 64MB fp16.

typedef unsigned short u16;
typedef __bf16 bf16x8 __attribute__((ext_vector_type(8)));
typedef float f32x4 __attribute__((ext_vector_type(4)));
typedef unsigned short us8 __attribute__((ext_vector_type(8)));

__device__ __forceinline__ u16 f2bf(float f) {
    union { float f; unsigned u; } x; x.f = f;
    unsigned r = x.u + 0x7FFFu + ((x.u >> 16) & 1u);   // RNE
    return (u16)(r >> 16);
}
__device__ __forceinline__ u16 f2h(float f) {
    union { _Float16 h; u16 u; } c; c.h = (_Float16)f;
    return c.u;
}
__device__ __forceinline__ float h2f(u16 b) {
    union { u16 u; _Float16 h; } c; c.u = b;
    return (float)c.h;
}

__device__ __forceinline__ void gload_lds16(const void* g, void* l) {
    __builtin_amdgcn_global_load_lds(
        (const __attribute__((address_space(1))) unsigned*)g,
        (__attribute__((address_space(3))) unsigned*)l, 16, 0, 0);
}

// 32-bit LDS byte offset of a __shared__ object (addrspace(3) ptrs are 32-bit)
__device__ __forceinline__ unsigned lds_off(const void* p) {
    return (unsigned)(size_t)(const __attribute__((address_space(3))) char*)p;
}
// opaque LDS read: no alias edge to global_load_lds -> no compiler vmcnt drain
__device__ __forceinline__ bf16x8 ds_read16(unsigned a) {
    bf16x8 r;
    asm volatile("ds_read_b128 %0, %1" : "=v"(r) : "v"(a));
    return r;
}

// ---------------------------------------------------------------- cast x -> bf16
__global__ void cast_x(const float* __restrict__ x, u16* __restrict__ o) {
    int i = blockIdx.x * 256 + threadIdx.x;          // float4 index
    float4 v = ((const float4*)x)[i];
    ushort4 u;
    u.x = f2bf(v.x); u.y = f2bf(v.y); u.z = f2bf(v.z); u.w = f2bf(v.w);
    ((ushort4*)o)[i] = u;
}

// ------------------------------------------------- W[e][n] -> WT[n][e] bf16, x3
__global__ void transpose_cast_w(const float* __restrict__ Wq,
                                 const float* __restrict__ Wk,
                                 const float* __restrict__ Wv,
                                 u16* __restrict__ WT) {
    __shared__ float tile[32][33];
    const float* W = (blockIdx.z == 0) ? Wq : (blockIdx.z == 1) ? Wk : Wv;
    u16* T = WT + (size_t)blockIdx.z * 1048576;
    int n0 = blockIdx.x * 32, e0 = blockIdx.y * 32;
    int tx = threadIdx.x, ty = threadIdx.y;
#pragma unroll
    for (int j = 0; j < 4; ++j) {
        int e = ty + j * 8;
        tile[e][tx] = W[(size_t)(e0 + e) * 1024 + (n0 + tx)];
    }
    __syncthreads();
#pragma unroll
    for (int j = 0; j < 4; ++j) {
        int n = ty + j * 8;
        T[(size_t)(n0 + n) * 1024 + (e0 + tx)] = f2bf(tile[tx][n]);
    }
}

// ----------------------------------------------------- lengths[b] from x rows
__global__ void calc_lengths(const float* __restrict__ x, int* __restrict__ len) {
    int b = blockIdx.x, tid = threadIdx.x;
    int cnt = 0;
    for (int t = tid; t < 2048; t += 256) {
        float4 v = *(const float4*)(x + ((size_t)b * 2048 + t) * 1024);
        cnt += (v.x != 0.f || v.y != 0.f || v.z != 0.f || v.w != 0.f) ? 1 : 0;
    }
#pragma unroll
    for (int off = 32; off; off >>= 1) cnt += __shfl_xor(cnt, off);
    __shared__ int red[4];
    int wid = tid >> 6, lane = tid & 63;
    if (!lane) red[wid] = cnt;
    __syncthreads();
    if (tid == 0) len[b] = red[0] + red[1] + red[2] + red[3];
}

// ------------------------------------------------------------- bf16 NT GEMM
// 128x128 tile, BK=64, 2 barriers/K-tile, 2 blocks/CU. C[m,n]=sum_k A[m,k]B[n,k].
// MODE 3: fused-QKV, 1-D grid (3072) with XCD-strip decode; region from bn.
// MODE 4: energy fp16; n-blocks bn>=len return; m-blocks bm>=len store zeros
// MODE 5: PV fp32; K clamped to round64(len)

#define SBAR0 __builtin_amdgcn_sched_barrier(0)

#define STAGE_T(KT, BUF) do { \
  _Pragma("unroll") for (int j_ = 0; j_ < 4; ++j_) \
      gload_lds16(A + offA[j_] + (size_t)(KT) * 64, &As[BUF][ldsC[j_]]); \
  _Pragma("unroll") for (int j_ = 0; j_ < 4; ++j_) \
      gload_lds16(B + offB[j_] + (size_t)(KT) * 64, &Bs[BUF][ldsC[j_]]); \
} while (0)

#define LD_A(S) do { \
  _Pragma("unroll") for (int mt_ = 0; mt_ < 4; ++mt_) \
    af[S][mt_] = ds_read16(rowA[mt_] + ((S) ? ps1 : ps0)); \
} while (0)
#define LD_B(S) do { \
  _Pragma("unroll") for (int nt_ = 0; nt_ < 4; ++nt_) \
    bf[S][nt_] = ds_read16(rowB[nt_] + ((S) ? ps1 : ps0)); \
} while (0)

#define MFMA_S(S) do { \
  _Pragma("unroll") for (int mt_ = 0; mt_ < 4; ++mt_) \
  _Pragma("unroll") for (int nt_ = 0; nt_ < 4; ++nt_) \
    acc[mt_][nt_] = __builtin_amdgcn_mfma_f32_16x16x32_bf16( \
        af[S][mt_], bf[S][nt_], acc[mt_][nt_], 0, 0, 0); \
} while (0)

template <int MODE>
__global__ __launch_bounds__(256, 2)   // 4 waves; 2 blocks/CU (64 KiB LDS each)
void gemm_bt(const u16* __restrict__ A, int lda, size_t sA,
             const u16* __restrict__ B, int ldb, size_t sB,
             void* __restrict__ Cv, void* __restrict__ Cv2,
             int ldc, size_t sC, int Kdim, const int* __restrict__ lenp) {
    __shared__ u16 As[2][128 * 64];    // 32 KiB (16 KiB per parity buffer)
    __shared__ u16 Bs[2][128 * 64];    // 32 KiB
    const int tid = threadIdx.x;
    const int bz  = blockIdx.z;
    A += (size_t)bz * sA;
    B += (size_t)bz * sB;

    // block -> (bm, bn). MODE 3: 1-D grid, XCD-aware decode (T1): hw id
    // round-robins XCDs (xcd = id%8); XCD c runs x-strip c then c+8, each
    // strip = 8 x-values x 24 y in y-major order -> A strip (2 MB) L2-hot.
    size_t bm, bn;
    if (MODE == 3) {
        int c    = blockIdx.x & 7;
        int s    = blockIdx.x >> 3;          // 0..383
        int half = (s >= 192) ? 1 : 0;
        int s2   = s - half * 192;           // 0..191
        int bx   = ((c + (half << 3)) << 3) + (s2 & 7);   // 0..127
        bm = (size_t)bx * 128;
        bn = (size_t)(s2 >> 3) * 128;        // y = 0..23
    } else {
        bm = (size_t)blockIdx.x * 128;
        bn = (size_t)blockIdx.y * 128;
    }

    bool skip = false;
    int kEnd = Kdim;
    if (MODE == 3) {
        int lenz = lenp[bm >> 11];
        skip = ((int)(bm & 2047) >= lenz);           // whole tile rows are zero
    } else if (MODE == 4) {
        int lenz = lenp[bz];
        if ((int)bn >= lenz) return;                 // cols fully masked: unread
        skip = ((int)bm >= lenz);                    // Q rows zero -> energy 0
    } else if (MODE == 5) {
        int lenz = lenp[bz];
        int r64 = (lenz + 63) & ~63;
        kEnd = r64 < Kdim ? r64 : Kdim;              // P cols >= len are zeros
    }

    const int wid = tid >> 6, lane = tid & 63;
    const int wm = wid >> 1, wn = wid & 1;           // 2M x 2N wave grid
    const int q = lane >> 4, r = lane & 15;

    // staging: each matrix tile = 1024 x 16B chunks; thread owns c = j*256+tid.
    // chunk c -> linear LDS byte c*16 (wave-contiguous); global source column
    // pre-swizzled so LDS[linear] == swizzled layout (rule #21).
    size_t offA[4], offB[4]; int ldsC[4];
#pragma unroll
    for (int j = 0; j < 4; ++j) {
        int c = j * 256 + tid;
        int row = c >> 3;
        int c16 = (c & 7) ^ (row & 7);               // involution swizzle
        offA[j] = (size_t)(bm + row) * lda + c16 * 8;
        offB[j] = (size_t)(bn + row) * ldb + c16 * 8;
        ldsC[j] = c * 8;
    }

    // precomputed LDS read addresses (buf0): row base + swizzled 16B chunk
    unsigned rowA[4], rowB[4], swz0, swz1;
    {
        unsigned asB = lds_off(&As[0][0]), bsB = lds_off(&Bs[0][0]);
        swz0 = (unsigned)((q ^ (r & 7)) * 16);
        swz1 = (unsigned)(((q + 4) ^ (r & 7)) * 16);
#pragma unroll
        for (int mt = 0; mt < 4; ++mt)
            rowA[mt] = asB + (unsigned)((wm * 64 + mt * 16 + r) * 128);
#pragma unroll
        for (int nt = 0; nt < 4; ++nt)
            rowB[nt] = bsB + (unsigned)((wn * 64 + nt * 16 + r) * 128);
    }

    f32x4 acc[4][4] = {};

    if (!skip) {
        const int NT = kEnd >> 6;                    // >= 16 always (len>=1024)
        STAGE_T(0, 0);
        STAGE_T(1, 1);
        asm volatile("s_waitcnt vmcnt(8)" ::: "memory");   // tile 0 landed
        SBAR0; __builtin_amdgcn_s_barrier(); SBAR0;
        for (int t = 0; t < NT; ++t) {
            const int p = t & 1;
            const unsigned ps0 = (unsigned)(p << 14) + swz0;
            const unsigned ps1 = (unsigned)(p << 14) + swz1;
            bf16x8 af[2][4], bf[2][4];
            // 16 ds_reads of buf[p]: khalf0 (A,B) then khalf1 (A,B)
            LD_A(0); LD_B(0);
            LD_A(1); LD_B(1);
            asm volatile("s_waitcnt lgkmcnt(8)" ::: "memory");  // khalf0 ready
            SBAR0;
            __builtin_amdgcn_s_setprio(1);
            MFMA_S(0);                              // khalf1 lands underneath
            __builtin_amdgcn_s_setprio(0);
            SBAR0;
            asm volatile("s_waitcnt lgkmcnt(0)" ::: "memory");  // all reads done
            SBAR0;
            __builtin_amdgcn_s_barrier();           // #1: block-wide read drain
            SBAR0;
            // WAR-safe NOW: stage tile t+2 into buf[p]; overlaps MFMA_S(1)
            if (t + 2 < NT) STAGE_T(t + 2, p);
            SBAR0;
            __builtin_amdgcn_s_setprio(1);
            MFMA_S(1);                              // operands already in regs
            __builtin_amdgcn_s_setprio(0);
            SBAR0;
            // counted vmcnt: outstanding {t+1:8, t+2:8} -> 8 == t+1 landed
            if (t + 2 < NT)      asm volatile("s_waitcnt vmcnt(8)" ::: "memory");
            else if (t + 1 < NT) asm volatile("s_waitcnt vmcnt(0)" ::: "memory");
            __builtin_amdgcn_s_barrier();           // #2: tile t+1 visible to all
            SBAR0;
        }
    }

    // C/D layout per 16x16 fragment: col = lane&15, row = (lane>>4)*4 + i
    // acc[mt][nt]: row = wm*64 + mt*16 + q*4 + i, col = wn*64 + nt*16 + r
    if (MODE == 5) {
        float* C = (float*)Cv + (size_t)bz * sC;
#pragma unroll
        for (int mt = 0; mt < 4; ++mt) {
            size_t row = bm + wm * 64 + mt * 16 + q * 4;
#pragma unroll
            for (int nt = 0; nt < 4; ++nt) {
                size_t col = bn + wn * 64 + nt * 16 + r;
#pragma unroll
                for (int i = 0; i < 4; ++i)
                    C[(row + i) * (size_t)ldc + col] = acc[mt][nt][i];
            }
        }
    } else if (MODE == 4) {
        u16* C = (u16*)Cv + (size_t)bz * sC;
#pragma unroll
        for (int mt = 0; mt < 4; ++mt) {
            size_t row = bm + wm * 64 + mt * 16 + q * 4;
#pragma unroll
            for (int nt = 0; nt < 4; ++nt) {
                size_t col = bn + wn * 64 + nt * 16 + r;
#pragma unroll
                for (int i = 0; i < 4; ++i)
                    C[(row + i) * (size_t)ldc + col] = f2h(acc[mt][nt][i]);
            }
        }
    } else {  // MODE 3: fused QKV epilogue, region uniform per block
        int region = (int)(bn >> 10);                 // 0:Q 1:K 2:V (1024 cols)
        if (region < 2) {
            u16* C = (u16*)Cv + (size_t)region * 16777216;  // Q or K [16384x1024]
            size_t cb = bn - (size_t)region * 1024;
#pragma unroll
            for (int mt = 0; mt < 4; ++mt) {
                size_t row = bm + wm * 64 + mt * 16 + q * 4;
#pragma unroll
                for (int nt = 0; nt < 4; ++nt) {
                    size_t col = cb + wn * 64 + nt * 16 + r;
#pragma unroll
                    for (int i = 0; i < 4; ++i)
                        C[(row + i) * 1024 + col] = f2bf(acc[mt][nt][i]);
                }
            }
        } else {
            // VT[b][d][t] = V[b*2048+t][d]; b = bm>>11 is BLOCK-UNIFORM
            // (128-row tiles never straddle the 2048-row batch boundary).
            // Each lane owns 4 consecutive t at fixed d -> one ushort4 store.
            u16* Cb = (u16*)Cv2 + (bm >> 11) * (size_t)(1024 * 2048)
                      + (bn - 2048) * 2048 + (bm & 2047);
#pragma unroll
            for (int nt = 0; nt < 4; ++nt) {
                int cI = wn * 64 + nt * 16 + r;
#pragma unroll
                for (int mt = 0; mt < 4; ++mt) {
                    int tI = wm * 64 + mt * 16 + q * 4;
                    ushort4 o;
                    o.x = f2bf(acc[mt][nt][0]);
                    o.y = f2bf(acc[mt][nt][1]);
                    o.z = f2bf(acc[mt][nt][2]);
                    o.w = f2bf(acc[mt][nt][3]);
                    *(ushort4*)(Cb + (size_t)cI * 2048 + tI) = o;
                }
            }
        }
    }
}

// ---- masked softmax, ONE ROW PER WAVE: fp16 row in, bf16 P in place (full row)
// Read and write both use us8 chunks: chunk c = j*64+lane covers cols c*8..c*8+7.
__global__ void softmax_rows_w(u16* __restrict__ E, const int* __restrict__ lengths) {
    int row  = blockIdx.x * 4 + (threadIdx.x >> 6);   // 16384 rows, 4 waves/block
    int lane = threadIdx.x & 63;
    int len  = lengths[row >> 11];
    u16* e = E + (size_t)row * 2048;

    float vals[32];
#pragma unroll
    for (int j = 0; j < 4; ++j) {
        us8 v = ((const us8*)e)[j * 64 + lane];
#pragma unroll
        for (int w = 0; w < 8; ++w) vals[j * 8 + w] = h2f(v[w]);
    }

    float m = -3.4e38f;
#pragma unroll
    for (int j = 0; j < 4; ++j) {
        int base = (j * 64 + lane) * 8;
#pragma unroll
        for (int w = 0; w < 8; ++w)
            if (base + w < len) m = fmaxf(m, vals[j * 8 + w]);
    }
#pragma unroll
    for (int off = 32; off; off >>= 1) m = fmaxf(m, __shfl_xor(m, off));

    const float C = 0.18033688011112042f;   // log2(e)/8  (scale 1/sqrt(64))
    float p[32]; float s = 0.f;
#pragma unroll
    for (int j = 0; j < 4; ++j) {
        int base = (j * 64 + lane) * 8;
#pragma unroll
        for (int w = 0; w < 8; ++w) {
            float v = (base + w < len) ? exp2f((vals[j * 8 + w] - m) * C) : 0.f;
            p[j * 8 + w] = v;
            s += v;
        }
    }
#pragma unroll
    for (int off = 32; off; off >>= 1) s += __shfl_xor(s, off);
    float rinv = 1.0f / s;

    // bf16 P over the fp16 row, identical chunk mapping as the read
#pragma unroll
    for (int j = 0; j < 4; ++j) {
        us8 o;
#pragma unroll
        for (int w = 0; w < 8; ++w) o[w] = f2bf(p[j * 8 + w] * rinv);
        ((us8*)e)[j * 64 + lane] = o;
    }
}

// ------------------------------------------------------------------ launch
extern "C" void kernel_launch(void* const* d_in, const int* in_sizes, int n_in,
                              void* d_out, int out_size, void* d_ws, size_t ws_size,
                              hipStream_t stream) {
    const float* x  = (const float*)d_in[0];
    const float* Wq = (const float*)d_in[1];
    const float* Wk = (const float*)d_in[2];
    const float* Wv = (const float*)d_in[3];
    float* out = (float*)d_out;
    char* ws = (char*)d_ws;

    const size_t SB  = 2097152;      // u16 elems per batch [2048x1024]
    const size_t SBe = 4194304;      // u16 elems per batch energy [2048x2048]

    // ws: lengths 256B | x16 32MB | WT 6MB | VT 32MB | E 64MB fp16 = 140,509,440 B
    if (ws_size < 140509440ULL) return;
    int* lengths = (int*)ws;
    u16* x16 = (u16*)(ws + 256);
    u16* WT  = (u16*)(ws + 33554688);
    u16* VT  = (u16*)(ws + 39846144);
    u16* E   = (u16*)(ws + 73400576);
    u16* Qb  = (u16*)d_out;                          // Q,K parked in d_out (64 MiB)
    u16* Kb  = Qb + 16777216;

    cast_x<<<dim3(16384), dim3(256), 0, stream>>>(x, x16);
    transpose_cast_w<<<dim3(32, 32, 3), dim3(32, 8), 0, stream>>>(Wq, Wk, Wv, WT);
    calc_lengths<<<dim3(8), dim3(256), 0, stream>>>(x, lengths);

    // fused QKV: x16[16384x1024] @ WT[3072x1024]^T -> Q,K (d_out) + VT (ws)
    // 1-D grid, XCD-aware decode inside the kernel (T1)
    gemm_bt<3><<<dim3(3072, 1, 1), 256, 0, stream>>>(x16, 1024, 0, WT, 1024, 0,
                                                     Qb, VT, 1024, 0, 1024, lengths);

    // energy[b] = Q_b K_b^T -> fp16 E; bn>=len skipped, bm>=len zero-filled
    gemm_bt<4><<<dim3(16, 16, 8), 256, 0, stream>>>(Qb, 1024, SB, Kb, 1024, SB,
                                                    E, nullptr, 2048, SBe, 1024, lengths);

    // masked softmax -> bf16 P in place (one row per wave)
    softmax_rows_w<<<dim3(4096), dim3(256), 0, stream>>>(E, lengths);

    // out[b] = P_b V_b = P_b (VT_b)^T; K clamped to round64(len[b])
    gemm_bt<5><<<dim3(16, 8, 8), 256, 0, stream>>>(E, 2048, SBe, VT, 2048, SB,
                                                   out, nullptr, 1024, SB, 2048, lengths);
}